// Round 7
// baseline (306.963 us; speedup 1.0000x reference)
//
#include <hip/hip_runtime.h>
#include <math.h>

#define SEQ   2048
#define BATCH 4
#define DIM   1024
#define NHEAD 16
#define HD    64
#define NQKV  3072   // 3*DIM
#define MROWS (BATCH*SEQ)   // 8192
#define GK    1024   // GEMM K
#define QKP   2048   // q,k packed pitch (v stored transposed separately)

typedef __attribute__((ext_vector_type(8))) short bf16x8;
typedef __attribute__((ext_vector_type(4))) float f32x4;
typedef __attribute__((ext_vector_type(4))) unsigned int u32x4;
typedef unsigned int u32;

// q-scale: (1/sqrt(64)) * log2(e)
#define QSCALE 0.18033688011112042f
#define INV2PI 0.15915494309189535f
#define TWOPI  6.283185307179586f

#if __has_builtin(__builtin_amdgcn_exp2f)
#define EXP2(x) __builtin_amdgcn_exp2f(x)
#else
#define EXP2(x) exp2f(x)
#endif

__device__ inline unsigned short f2bf(float f) {
    unsigned u = __builtin_bit_cast(unsigned, f);
    u += 0x7fff + ((u >> 16) & 1);      // round-to-nearest-even
    return (unsigned short)(u >> 16);
}
__device__ inline float bf2f(unsigned short h) {
    unsigned u = ((unsigned)h) << 16;
    return __builtin_bit_cast(float, u);
}
__device__ inline void split2(float v, unsigned short& h, unsigned short& l) {
    h = f2bf(v);
    l = f2bf(v - bf2f(h));
}
__device__ inline void gl_lds16(const void* g, void* l) {
    __builtin_amdgcn_global_load_lds(
        (const __attribute__((address_space(1))) unsigned int*)g,
        (__attribute__((address_space(3))) unsigned int*)l, 16, 0, 0);
}

// ---------------------------------------------------------------------------
// Kernel 1: prep = split_x + split_wT merged.
// ---------------------------------------------------------------------------
__global__ __launch_bounds__(256) void prep(const float* __restrict__ X,
                                            const float* __restrict__ W,
                                            unsigned short* __restrict__ Xh,
                                            unsigned short* __restrict__ Xl,
                                            unsigned short* __restrict__ WhT,
                                            unsigned short* __restrict__ WlT)
{
    __shared__ unsigned short Th[32 * 36];
    __shared__ unsigned short Tl[32 * 36];
    const int bx = blockIdx.x;
    const int tid = threadIdx.x;

    if (bx < 4096) {
        size_t base = ((size_t)bx * 256 + tid) * 8;
        float4 a = *reinterpret_cast<const float4*>(&X[base]);
        float4 b = *reinterpret_cast<const float4*>(&X[base + 4]);
        float v[8] = {a.x, a.y, a.z, a.w, b.x, b.y, b.z, b.w};
        unsigned short h[8], l[8];
#pragma unroll
        for (int j = 0; j < 8; ++j) split2(v[j], h[j], l[j]);
        *reinterpret_cast<bf16x8*>(&Xh[base]) = *reinterpret_cast<bf16x8*>(h);
        *reinterpret_cast<bf16x8*>(&Xl[base]) = *reinterpret_cast<bf16x8*>(l);
        return;
    }

    const int b2 = bx - 4096;
    const int n0 = (b2 % 96) * 32;
    const int k0 = (b2 / 96) * 32;
    {
        int kr = tid >> 3;
        int nc = (tid & 7) * 4;
        float4 v = *reinterpret_cast<const float4*>(&W[(size_t)(k0 + kr) * NQKV + n0 + nc]);
        float vv[4] = {v.x, v.y, v.z, v.w};
#pragma unroll
        for (int j = 0; j < 4; ++j) {
            unsigned short h, l;
            split2(vv[j], h, l);
            Th[kr * 36 + nc + j] = h;
            Tl[kr * 36 + nc + j] = l;
        }
    }
    __syncthreads();
    {
        int nl = tid >> 3;
        int kc = (tid & 7) * 4;
        ushort4 h, l;
        h.x = Th[(kc + 0) * 36 + nl]; l.x = Tl[(kc + 0) * 36 + nl];
        h.y = Th[(kc + 1) * 36 + nl]; l.y = Tl[(kc + 1) * 36 + nl];
        h.z = Th[(kc + 2) * 36 + nl]; l.z = Tl[(kc + 2) * 36 + nl];
        h.w = Th[(kc + 3) * 36 + nl]; l.w = Tl[(kc + 3) * 36 + nl];
        size_t o = (size_t)(n0 + nl) * GK + k0 + kc;
        *reinterpret_cast<ushort4*>(&WhT[o]) = h;
        *reinterpret_cast<ushort4*>(&WlT[o]) = l;
    }
}

// ---------------------------------------------------------------------------
// Kernel 2: split-bf16 MFMA GEMM, BK=32 double-buffered (loads hidden under
// compute, ONE barrier per K-step), fused fast-RoPE epilogue.
//  LDS: 2 buf x 4 planes x [128 rows x 32 cols] bf16 = 64 KB.
//  Swizzle (conflict-free b128 frag reads, verified): within each 16-row
//  1 KB segment, global (r,q) chunk lives at row-pair R2=r>>1, chunk
//  u = ((r&1)*4+q) ^ R2.  gl_lds lane l -> R2=l>>3, t=(l&7)^R2,
//  r=R2*2+(t>>2), q=t&3.
// ---------------------------------------------------------------------------
__global__ __launch_bounds__(256, 2) void gemm_split(
    const unsigned short* __restrict__ Xh, const unsigned short* __restrict__ Xl,
    const unsigned short* __restrict__ WhT, const unsigned short* __restrict__ WlT,
    const float* __restrict__ bias, unsigned short* __restrict__ qkB,
    unsigned short* __restrict__ VTo)
{
    __shared__ __align__(16) unsigned short lds[2 * 4 * 128 * 32];  // 64 KB

    const int tid  = threadIdx.x;
    const int w    = tid >> 6;
    const int lane = tid & 63;
    const int quad = lane >> 4;
    const int l16  = lane & 15;
    const int n0 = blockIdx.x * 128;
    const int m0 = blockIdx.y * 128;
    const int wm = (w >> 1) * 64;
    const int wn = (w & 1) * 64;

    // staging lane->global mapping (see header comment)
    const int sR2 = lane >> 3;
    const int sT  = (lane & 7) ^ sR2;
    const int sRo = sR2 * 2 + (sT >> 2);   // row within segment
    const int sQ  = (sT & 3) * 8;          // global col offset (elems)

    // stage one plane (128x32) into ldsPlane for K-offset k0
    auto stageP = [&](const unsigned short* __restrict__ g, unsigned short* lp,
                      int row0, int k0) {
#pragma unroll
        for (int p = 0; p < 2; ++p) {
            int seg = p * 4 + w;
            gl_lds16(g + (size_t)(row0 + seg * 16 + sRo) * GK + k0 + sQ,
                     lp + seg * 512);
        }
    };
    auto stageAll = [&](unsigned short* buf, int k0) {
        stageP(Xh,  buf,            m0, k0);
        stageP(Xl,  buf + 4096,     m0, k0);
        stageP(WhT, buf + 8192,     n0, k0);
        stageP(WlT, buf + 12288,    n0, k0);
    };

    // frag-read offset within a segment (elems)
    const int fSwz = (l16 >> 1) & 7;
    const int fOff = fSwz * 64 + (((((l16 & 1) << 2) | quad)) ^ fSwz) * 8;
    const int segA = wm >> 4;   // segment base for this wave's A rows
    const int segB = wn >> 4;

    f32x4 acc[4][4];
#pragma unroll
    for (int mi = 0; mi < 4; ++mi)
#pragma unroll
        for (int ni = 0; ni < 4; ++ni) acc[mi][ni] = (f32x4){0.f, 0.f, 0.f, 0.f};

    stageAll(lds, 0);

    for (int kt = 0; kt < GK / 32; ++kt) {
        __syncthreads();   // drains current buf's loads; prev buf reads done
        unsigned short* cur = lds + (kt & 1) * 16384;
        if (kt < GK / 32 - 1)
            stageAll(lds + ((kt & 1) ^ 1) * 16384, (kt + 1) * 32);

        bf16x8 ah[4], al[4], bh[4], bl[4];
#pragma unroll
        for (int t = 0; t < 4; ++t) {
            int oa = (segA + t) * 512 + fOff;
            int ob = (segB + t) * 512 + fOff;
            ah[t] = *reinterpret_cast<const bf16x8*>(&cur[oa]);
            al[t] = *reinterpret_cast<const bf16x8*>(&cur[4096 + oa]);
            bh[t] = *reinterpret_cast<const bf16x8*>(&cur[8192 + ob]);
            bl[t] = *reinterpret_cast<const bf16x8*>(&cur[12288 + ob]);
        }
#pragma unroll
        for (int mi = 0; mi < 4; ++mi)
#pragma unroll
            for (int ni = 0; ni < 4; ++ni) {
                acc[mi][ni] = __builtin_amdgcn_mfma_f32_16x16x32_bf16(
                    al[mi], bh[ni], acc[mi][ni], 0, 0, 0);
                acc[mi][ni] = __builtin_amdgcn_mfma_f32_16x16x32_bf16(
                    ah[mi], bl[ni], acc[mi][ni], 0, 0, 0);
                acc[mi][ni] = __builtin_amdgcn_mfma_f32_16x16x32_bf16(
                    ah[mi], bh[ni], acc[mi][ni], 0, 0, 0);
            }
    }

    // ---- epilogue: +bias; q/k: fused RoPE (fast sincos) then bf16 once;
    // v: transposed store ----
#pragma unroll
    for (int ni = 0; ni < 4; ++ni) {
        int n = n0 + wn + ni * 16 + l16;
        float bv = bias[n];
        if (n < 2 * DIM) {
            float scale = (n < DIM) ? QSCALE : 1.0f;
            bool doRope = ((n & 63) < 32);        // uniform per ni
            float invf = 0.f;
            if (doRope) {
                int pair = (n & 31) >> 1;
                invf = exp2f(-(float)pair * (13.287712379549449f / 16.0f)) * INV2PI;
            }
#pragma unroll
            for (int mi = 0; mi < 4; ++mi) {
                int m = m0 + wm + mi * 16 + quad * 4;
#pragma unroll
                for (int r = 0; r < 4; ++r) {
                    float v = acc[mi][ni][r] + bv;
                    float o = v;
                    if (doRope) {
                        float partner = __shfl_xor(v, 1, 64);  // n^1 in lane l16^1
                        int token = (m + r) & (SEQ - 1);
                        float rev = (float)token * invf;
                        rev -= floorf(rev);
                        float ang = rev * TWOPI;
                        float s = __sinf(ang), c = __cosf(ang);
                        o = (n & 1) ? (v * c + partner * s) : (v * c - partner * s);
                    }
                    qkB[(size_t)(m + r) * QKP + n] = f2bf(o * scale);
                }
            }
        } else {
            int d  = n & 63;
            int hh = (n - 2 * DIM) >> 6;
#pragma unroll
            for (int mi = 0; mi < 4; ++mi) {
                int m = m0 + wm + mi * 16 + quad * 4;
                int bhh = (m >> 11) * 16 + hh;
                ushort4 pkv;
                pkv.x = f2bf(acc[mi][ni][0] + bv);
                pkv.y = f2bf(acc[mi][ni][1] + bv);
                pkv.z = f2bf(acc[mi][ni][2] + bv);
                pkv.w = f2bf(acc[mi][ni][3] + bv);
                *reinterpret_cast<ushort4*>(
                    &VTo[((size_t)bhh * HD + d) * SEQ + (m & (SEQ - 1))]) = pkv;
            }
        }
    }
}

// ---------------------------------------------------------------------------
// Kernel 3: MFMA flash attention, S^T form (unchanged from R6).
// ---------------------------------------------------------------------------
__global__ __launch_bounds__(256, 4) void attn_mfma3(const unsigned short* __restrict__ qkB,
                                                     const unsigned short* __restrict__ VT,
                                                     float* __restrict__ out)
{
    __shared__ __align__(16) unsigned short Ks[128 * 64];   // K (and Q staging)
    __shared__ __align__(16) unsigned short Vt[64 * 128];   // V^T tile [d][key]

    const int tid  = threadIdx.x;
    const int w    = tid >> 6;
    const int lane = tid & 63;
    const int quad = lane >> 4;
    const int l16  = lane & 15;
    const int bh  = blockIdx.x;       // 64  -> XCD = bh % 8
    const int qtb = blockIdx.y;       // 16
    const int bi = bh >> 4, h = bh & 15;
    const int m0 = qtb * 128;

    const unsigned short* Qg  = qkB + (size_t)bi * SEQ * QKP + h * HD;
    const unsigned short* Kg  = Qg + DIM;
    const unsigned short* VTg = VT + (size_t)bh * HD * SEQ;

    // ---- stage Q into Ks (slot-swizzled), read Q frags ----
#pragma unroll
    for (int p = 0; p < 4; ++p) {
        int seg = p * 4 + w;
        int r = seg * 8 + (lane >> 3);
        int s = (lane & 7) ^ (r & 7);
        gl_lds16(Qg + (size_t)(m0 + r) * QKP + s * 8, Ks + seg * 512);
    }
    __syncthreads();

    bf16x8 qf[2][2];
#pragma unroll
    for (int qt = 0; qt < 2; ++qt)
#pragma unroll
        for (int ks = 0; ks < 2; ++ks)
            qf[qt][ks] = *reinterpret_cast<const bf16x8*>(
                &Ks[(w * 32 + qt * 16 + l16) * 64 + ((ks * 4 + quad) ^ (l16 & 7)) * 8]);

    // ones-row A-operand: C row 0 = column sums of B
    const u32 onepair = (l16 == 0) ? 0x3F803F80u : 0u;
    const bf16x8 ones_a = __builtin_bit_cast(
        bf16x8, (u32x4){onepair, onepair, onepair, onepair});

    f32x4 y[2][4];
#pragma unroll
    for (int qt = 0; qt < 2; ++qt)
#pragma unroll
        for (int dt = 0; dt < 4; ++dt) y[qt][dt] = (f32x4){0.f, 0.f, 0.f, 0.f};
    f32x4 yl[2] = {(f32x4){0.f, 0.f, 0.f, 0.f}, (f32x4){0.f, 0.f, 0.f, 0.f}};

    for (int c0 = 0; c0 < SEQ; c0 += 128) {
        __syncthreads();

        // ---- stage K with key permutation ----
#pragma unroll
        for (int p = 0; p < 4; ++p) {
            int seg = p * 4 + w;
            int r = seg * 8 + (lane >> 3);
            int a = (r & ~31) | (((r >> 2) & 3) << 3)
                  | (((r >> 4) & 1) << 2) | (r & 3);
            int s = (lane & 7) ^ (r & 7);
            gl_lds16(Kg + (size_t)(c0 + a) * QKP + s * 8, Ks + seg * 512);
        }
        // ---- stage V^T ----
#pragma unroll
        for (int p = 0; p < 4; ++p) {
            int seg = p * 4 + w;
            int r = seg * 4 + (lane >> 4);
            int s = (lane & 15) ^ (r & 15);
            gl_lds16(VTg + (size_t)r * SEQ + c0 + s * 8, Vt + seg * 512);
        }
        __syncthreads();

        // ---- per 32-key group: QK^T (S^T), exp, pack, PV + l ----
#pragma unroll
        for (int ksp = 0; ksp < 4; ++ksp) {
            u32 pk[2][2][2];
#pragma unroll
            for (int t = 0; t < 2; ++t) {
                int kt = ksp * 2 + t;
                int krow = (kt * 16 + l16) * 64;
                bf16x8 kb0 = *reinterpret_cast<const bf16x8*>(
                    &Ks[krow + ((quad ^ (l16 & 7))) * 8]);
                bf16x8 kb1 = *reinterpret_cast<const bf16x8*>(
                    &Ks[krow + (((4 + quad) ^ (l16 & 7))) * 8]);
#pragma unroll
                for (int qt = 0; qt < 2; ++qt) {
                    f32x4 st = __builtin_amdgcn_mfma_f32_16x16x32_bf16(
                        kb0, qf[qt][0], (f32x4){0.f, 0.f, 0.f, 0.f}, 0, 0, 0);
                    st = __builtin_amdgcn_mfma_f32_16x16x32_bf16(
                        kb1, qf[qt][1], st, 0, 0, 0);
                    u32 e[4];
#pragma unroll
                    for (int r = 0; r < 4; ++r)
                        e[r] = __builtin_bit_cast(u32, EXP2(st[r]));
                    pk[qt][t][0] = __builtin_amdgcn_perm(e[1], e[0], 0x07060302u);
                    pk[qt][t][1] = __builtin_amdgcn_perm(e[3], e[2], 0x07060302u);
                }
            }
            bf16x8 pfragq[2];
#pragma unroll
            for (int qt = 0; qt < 2; ++qt) {
                pfragq[qt] = __builtin_bit_cast(
                    bf16x8, (u32x4){pk[qt][0][0], pk[qt][0][1], pk[qt][1][0], pk[qt][1][1]});
                yl[qt] = __builtin_amdgcn_mfma_f32_16x16x32_bf16(
                    ones_a, pfragq[qt], yl[qt], 0, 0, 0);
            }
#pragma unroll
            for (int dt = 0; dt < 4; ++dt) {
                int row = dt * 16 + l16;
                bf16x8 vfrag = *reinterpret_cast<const bf16x8*>(
                    &Vt[row * 128 + (((ksp * 4 + quad) ^ l16)) * 8]);
#pragma unroll
                for (int qt = 0; qt < 2; ++qt)
                    y[qt][dt] = __builtin_amdgcn_mfma_f32_16x16x32_bf16(
                        vfrag, pfragq[qt], y[qt][dt], 0, 0, 0);
            }
        }
    }

    // ---- final: broadcast l from C row 0, normalize, store ----
    float rsv[2];
#pragma unroll
    for (int qt = 0; qt < 2; ++qt) {
        float lv = __shfl(yl[qt][0], l16, 64);
        rsv[qt] = 1.f / lv;
    }

#pragma unroll
    for (int qt = 0; qt < 2; ++qt) {
        int token = m0 + w * 32 + qt * 16 + l16;
        size_t obase = ((size_t)(bi * SEQ + token)) * DIM + h * HD;
#pragma unroll
        for (int dt = 0; dt < 4; ++dt) {
            float4 o;
            o.x = y[qt][dt][0] * rsv[qt];
            o.y = y[qt][dt][1] * rsv[qt];
            o.z = y[qt][dt][2] * rsv[qt];
            o.w = y[qt][dt][3] * rsv[qt];
            *reinterpret_cast<float4*>(&out[obase + dt * 16 + quad * 4]) = o;
        }
    }
}

// ---------------------------------------------------------------------------
extern "C" void kernel_launch(void* const* d_in, const int* in_sizes, int n_in,
                              void* d_out, int out_size, void* d_ws, size_t ws_size,
                              hipStream_t stream)
{
    const float* x    = (const float*)d_in[0];
    const float* W    = (const float*)d_in[1];
    const float* bias = (const float*)d_in[2];
    float* out = (float*)d_out;

    unsigned short* qkB = (unsigned short*)d_ws;                  // 8192*2048
    unsigned short* VT  = qkB + (size_t)MROWS * QKP;              // 64*64*2048
    unsigned short* Xh  = VT + (size_t)BATCH * NHEAD * HD * SEQ;  // 8192*1024
    unsigned short* Xl  = Xh + (size_t)MROWS * GK;
    unsigned short* WhT = Xl + (size_t)MROWS * GK;                // 3072*1024
    unsigned short* WlT = WhT + (size_t)NQKV * GK;

    prep<<<4096 + 3072, 256, 0, stream>>>(x, W, Xh, Xl, WhT, WlT);
    gemm_split<<<dim3(NQKV / 128, MROWS / 128), 256, 0, stream>>>(Xh, Xl, WhT, WlT, bias, qkB, VT);
    attn_mfma3<<<dim3(BATCH * NHEAD, SEQ / 128), 256, 0, stream>>>(qkB, VT, out);
}